// Round 1
// baseline (19482.504 us; speedup 1.0000x reference)
//
#include <hip/hip_runtime.h>
#include <hip/hip_bf16.h>

#define TSTEPS 512
#define BATCH  64
#define DIM    512
#define G_SCAN 128
#define TK     64

// ---------- transpose 512x512 (hh -> hhT, o -> oT) ----------
__global__ void transpose512(const float* __restrict__ src, float* __restrict__ dst) {
    __shared__ float tile[32][33];
    const int bx = blockIdx.x * 32, by = blockIdx.y * 32;
    const int tx = threadIdx.x & 31, ty = threadIdx.x >> 5;   // 256 threads: ty 0..7
#pragma unroll
    for (int k = 0; k < 32; k += 8)
        tile[ty + k][tx] = src[(size_t)(by + ty + k) * DIM + bx + tx];
    __syncthreads();
#pragma unroll
    for (int k = 0; k < 32; k += 8)
        dst[(size_t)(bx + ty + k) * DIM + by + tx] = tile[tx][ty + k];
}

// ---------- XW = x @ xh + hb  -> written into d_out ----------
// M=32768, N=512, K=512. 64x64 tile / WG, 256 threads, 4x4 micro-tile.
__global__ __launch_bounds__(256) void gemm_xw(
    const float* __restrict__ X, const float* __restrict__ W,
    const float* __restrict__ bias, float* __restrict__ Out)
{
    __shared__ float As[16][68];   // [k][m], 16B-aligned rows (68*4=272)
    __shared__ float Bs[16][68];   // [k][n]
    const int tid = threadIdx.x;
    const int m0 = blockIdx.x * 64, n0 = blockIdx.y * 64;
    const int tx = tid & 15, ty = tid >> 4;
    float acc[4][4] = {};
    for (int k0 = 0; k0 < DIM; k0 += 16) {
        {   // A tile 64x16, store transposed
            int r = tid >> 2, c = (tid & 3) * 4;
            float4 v = *reinterpret_cast<const float4*>(X + (size_t)(m0 + r) * DIM + k0 + c);
            As[c + 0][r] = v.x; As[c + 1][r] = v.y; As[c + 2][r] = v.z; As[c + 3][r] = v.w;
        }
        {   // B tile 16x64
            int r = tid >> 4, c = (tid & 15) * 4;
            float4 v = *reinterpret_cast<const float4*>(W + (size_t)(k0 + r) * DIM + n0 + c);
            Bs[r][c + 0] = v.x; Bs[r][c + 1] = v.y; Bs[r][c + 2] = v.z; Bs[r][c + 3] = v.w;
        }
        __syncthreads();
#pragma unroll
        for (int k = 0; k < 16; ++k) {
            float4 a = *reinterpret_cast<const float4*>(&As[k][ty * 4]);
            float4 b = *reinterpret_cast<const float4*>(&Bs[k][tx * 4]);
            float av[4] = {a.x, a.y, a.z, a.w};
            float bv[4] = {b.x, b.y, b.z, b.w};
#pragma unroll
            for (int i = 0; i < 4; ++i)
#pragma unroll
                for (int j = 0; j < 4; ++j)
                    acc[i][j] = fmaf(av[i], bv[j], acc[i][j]);
        }
        __syncthreads();
    }
    float4 bv = *reinterpret_cast<const float4*>(bias + n0 + tx * 4);
    const float badd[4] = {bv.x, bv.y, bv.z, bv.w};
#pragma unroll
    for (int i = 0; i < 4; ++i) {
        float4 v;
        v.x = acc[i][0] + badd[0]; v.y = acc[i][1] + badd[1];
        v.z = acc[i][2] + badd[2]; v.w = acc[i][3] + badd[3];
        *reinterpret_cast<float4*>(Out + (size_t)(m0 + ty * 4 + i) * DIM + n0 + tx * 4) = v;
    }
}

// ---------- persistent scan kernel ----------
// G_SCAN WGs x 256 threads (4 waves). Wave wv of WG wg owns column col = wg*4+wv
// of BOTH hh (h-update) and o (y output). hh/o columns come from transposed
// copies via wave-uniform scalar loads. h broadcast goes through a XOR-swizzled
// LDS-staged tile; one staging pass feeds both accumulations.
// Iteration t: stage s_t -> acc_hh (-> s_{t+1}), acc_o (= y_{t-1}).
// d_out holds XW on entry; out[t-1] slice overwritten with y_{t-1} after arrival.
__global__ __launch_bounds__(256) void rnn_scan(
    const float* __restrict__ hhT, const float* __restrict__ oT,
    const float* __restrict__ h0, float* __restrict__ out,
    float* __restrict__ hbuf, unsigned int* __restrict__ cnt)
{
    const int tid  = threadIdx.x;
    const int wg   = blockIdx.x;
    const int lane = tid & 63;                                   // = batch index b
    const int wv   = __builtin_amdgcn_readfirstlane(tid >> 6);   // wave id 0..3 (SGPR)
    const int col  = wg * 4 + wv;
    const float4* hh4 = reinterpret_cast<const float4*>(hhT + (size_t)col * DIM);
    const float4* o4  = reinterpret_cast<const float4*>(oT  + (size_t)col * DIM);

    __shared__ float hs[BATCH * TK];   // 16 KB, XOR-swizzled

    for (int t = 0; t < TSTEPS; ++t) {
        const float* src = (t == 0) ? h0 : (hbuf + (size_t)(t % 3) * (BATCH * DIM));
        float ah0 = 0.f, ah1 = 0.f, ah2 = 0.f, ah3 = 0.f;
        float ao0 = 0.f, ao1 = 0.f, ao2 = 0.f, ao3 = 0.f;
        for (int kt = 0; kt < DIM / TK; ++kt) {
            __syncthreads();                       // hs reuse guard
#pragma unroll
            for (int i = 0; i < 4; ++i) {          // stage 64x64 tile
                int e  = (i * 256 + tid) * 4;
                int b  = e >> 6;
                int ko = e & 63;
                const float* gp = src + (t == 0 ? 0 : (size_t)b * DIM) + kt * TK + ko;
                float4 v = *reinterpret_cast<const float4*>(gp);
                int off = (b * TK + ko) ^ ((b & 7) << 2);
                *reinterpret_cast<float4*>(&hs[off]) = v;
            }
            __syncthreads();
            const int kb4 = kt * (TK / 4);
#pragma unroll
            for (int k4 = 0; k4 < TK / 4; ++k4) {
                int off = (lane * TK + k4 * 4) ^ ((lane & 7) << 2);
                float4 h4 = *reinterpret_cast<const float4*>(&hs[off]);
                float4 w4 = hh4[kb4 + k4];
                float4 v4 = o4[kb4 + k4];
                ah0 = fmaf(h4.x, w4.x, ah0); ah1 = fmaf(h4.y, w4.y, ah1);
                ah2 = fmaf(h4.z, w4.z, ah2); ah3 = fmaf(h4.w, w4.w, ah3);
                ao0 = fmaf(h4.x, v4.x, ao0); ao1 = fmaf(h4.y, v4.y, ao1);
                ao2 = fmaf(h4.z, v4.z, ao2); ao3 = fmaf(h4.w, v4.w, ao3);
            }
        }
        // s_{t+1}[lane][col] = relu(XW[t] + s_t@hh)
        float xw = out[((size_t)t * BATCH + lane) * DIM + col];
        float hnew = xw + ah0 + ah1 + ah2 + ah3;
        hnew = hnew > 0.f ? hnew : 0.f;
        hbuf[(size_t)((t + 1) % 3) * (BATCH * DIM) + (size_t)lane * DIM + col] = hnew;
        float yv = ao0 + ao1 + ao2 + ao3;          // = y_{t-1} (valid for t>=1)

        // ---- grid barrier (split-phase): arrive, do y-write, wait ----
        __threadfence();
        __syncthreads();
        if (tid == 0) atomicAdd(cnt, 1u);
        if (t >= 1) out[((size_t)(t - 1) * BATCH + lane) * DIM + col] = yv;
        if (tid == 0) {
            const unsigned target = (unsigned)G_SCAN * (unsigned)(t + 1);
            while (__hip_atomic_load(cnt, __ATOMIC_ACQUIRE, __HIP_MEMORY_SCOPE_AGENT) < target)
                __builtin_amdgcn_s_sleep(2);
        }
        __syncthreads();
        __threadfence();
    }
    // epilogue: y_{T-1} = s_T @ o
    {
        const float* src = hbuf + (size_t)(TSTEPS % 3) * (BATCH * DIM);
        float ao0 = 0.f, ao1 = 0.f, ao2 = 0.f, ao3 = 0.f;
        for (int kt = 0; kt < DIM / TK; ++kt) {
            __syncthreads();
#pragma unroll
            for (int i = 0; i < 4; ++i) {
                int e  = (i * 256 + tid) * 4;
                int b  = e >> 6;
                int ko = e & 63;
                float4 v = *reinterpret_cast<const float4*>(src + (size_t)b * DIM + kt * TK + ko);
                int off = (b * TK + ko) ^ ((b & 7) << 2);
                *reinterpret_cast<float4*>(&hs[off]) = v;
            }
            __syncthreads();
            const int kb4 = kt * (TK / 4);
#pragma unroll
            for (int k4 = 0; k4 < TK / 4; ++k4) {
                int off = (lane * TK + k4 * 4) ^ ((lane & 7) << 2);
                float4 h4 = *reinterpret_cast<const float4*>(&hs[off]);
                float4 v4 = o4[kb4 + k4];
                ao0 = fmaf(h4.x, v4.x, ao0); ao1 = fmaf(h4.y, v4.y, ao1);
                ao2 = fmaf(h4.z, v4.z, ao2); ao3 = fmaf(h4.w, v4.w, ao3);
            }
        }
        out[((size_t)(TSTEPS - 1) * BATCH + lane) * DIM + col] = ao0 + ao1 + ao2 + ao3;
    }
}

extern "C" void kernel_launch(void* const* d_in, const int* in_sizes, int n_in,
                              void* d_out, int out_size, void* d_ws, size_t ws_size,
                              hipStream_t stream) {
    const float* x  = (const float*)d_in[0];
    const float* xh = (const float*)d_in[1];
    const float* hh = (const float*)d_in[2];
    const float* hb = (const float*)d_in[3];
    const float* o  = (const float*)d_in[4];
    const float* h0 = (const float*)d_in[5];
    float* out = (float*)d_out;
    float* wsf = (float*)d_ws;

    unsigned int* cnt = (unsigned int*)d_ws;            // [0,256) bytes
    float* hbuf = wsf + 1024;                           // 3 * 64 * 512 floats
    float* hhT  = hbuf + 3 * BATCH * DIM;               // 512*512
    float* oT   = hhT + DIM * DIM;                      // 512*512

    hipMemsetAsync(d_ws, 0, 256, stream);
    transpose512<<<dim3(16, 16), 256, 0, stream>>>(hh, hhT);
    transpose512<<<dim3(16, 16), 256, 0, stream>>>(o, oT);
    gemm_xw<<<dim3(512, 8), 256, 0, stream>>>(x, xh, hb, out);
    rnn_scan<<<G_SCAN, 256, 0, stream>>>(hhT, oT, h0, out, hbuf, cnt);
}

// Round 3
// 3059.398 us; speedup vs baseline: 6.3681x; 6.3681x over previous
//
#include <hip/hip_runtime.h>
#include <hip/hip_bf16.h>

#define TSTEPS 512
#define BATCH  64
#define DIM    512
#define NWG    8

using short8 = __attribute__((ext_vector_type(8))) short;
using f32x4  = __attribute__((ext_vector_type(4))) float;

__device__ __forceinline__ unsigned short f2bf(float f) {
    unsigned u = __builtin_bit_cast(unsigned, f);
    unsigned r = (u + 0x7FFFu + ((u >> 16) & 1u)) >> 16;   // RNE
    return (unsigned short)r;
}

// ---------- XW = x @ xh + hb  -> written into d_out (fp32, verified round 0) ----------
__global__ __launch_bounds__(256) void gemm_xw(
    const float* __restrict__ X, const float* __restrict__ W,
    const float* __restrict__ bias, float* __restrict__ Out)
{
    __shared__ float As[16][68];
    __shared__ float Bs[16][68];
    const int tid = threadIdx.x;
    const int m0 = blockIdx.x * 64, n0 = blockIdx.y * 64;
    const int tx = tid & 15, ty = tid >> 4;
    float acc[4][4] = {};
    for (int k0 = 0; k0 < DIM; k0 += 16) {
        {
            int r = tid >> 2, c = (tid & 3) * 4;
            float4 v = *reinterpret_cast<const float4*>(X + (size_t)(m0 + r) * DIM + k0 + c);
            As[c + 0][r] = v.x; As[c + 1][r] = v.y; As[c + 2][r] = v.z; As[c + 3][r] = v.w;
        }
        {
            int r = tid >> 4, c = (tid & 15) * 4;
            float4 v = *reinterpret_cast<const float4*>(W + (size_t)(k0 + r) * DIM + n0 + c);
            Bs[r][c + 0] = v.x; Bs[r][c + 1] = v.y; Bs[r][c + 2] = v.z; Bs[r][c + 3] = v.w;
        }
        __syncthreads();
#pragma unroll
        for (int k = 0; k < 16; ++k) {
            float4 a = *reinterpret_cast<const float4*>(&As[k][ty * 4]);
            float4 b = *reinterpret_cast<const float4*>(&Bs[k][tx * 4]);
            float av[4] = {a.x, a.y, a.z, a.w};
            float bv[4] = {b.x, b.y, b.z, b.w};
#pragma unroll
            for (int i = 0; i < 4; ++i)
#pragma unroll
                for (int j = 0; j < 4; ++j)
                    acc[i][j] = fmaf(av[i], bv[j], acc[i][j]);
        }
        __syncthreads();
    }
    float4 bv = *reinterpret_cast<const float4*>(bias + n0 + tx * 4);
    const float badd[4] = {bv.x, bv.y, bv.z, bv.w};
#pragma unroll
    for (int i = 0; i < 4; ++i) {
        float4 v;
        v.x = acc[i][0] + badd[0]; v.y = acc[i][1] + badd[1];
        v.z = acc[i][2] + badd[2]; v.w = acc[i][3] + badd[3];
        *reinterpret_cast<float4*>(Out + (size_t)(m0 + ty * 4 + i) * DIM + n0 + tx * 4) = v;
    }
}

// ---------- persistent MFMA scan: 8 WGs x 4 waves ----------
// Wave wv of WG wg owns output cols [wg*64+wv*16, +16) of hh AND o, with both
// weight column-slices held in registers as bf16 B-fragments for the whole scan.
// Per step t: stage H_t (bf16, via relaxed agent atomic loads -> swizzled LDS),
// MFMA: acc_h = H_t@hh (-> H_{t+1}), acc_y = H_t@o (= y_{t-1}).
// H passes between steps through hbuf (4 rotating slots) at the coherence point.
__global__ __launch_bounds__(256, 1) void rnn_scan(
    const float* __restrict__ hh, const float* __restrict__ o,
    const float* __restrict__ h0, float* __restrict__ out,
    unsigned long long* __restrict__ hbuf, unsigned int* __restrict__ flags)
{
    const int tid  = threadIdx.x;
    const int wg   = blockIdx.x;
    const int lane = tid & 63;
    const int wv   = __builtin_amdgcn_readfirstlane(tid >> 6);
    const int ln15 = lane & 15, kg = lane >> 4;
    const int colw = wg * 64 + wv * 16 + ln15;           // this lane's output col

    __shared__ unsigned long long hsU[BATCH * DIM / 4];  // 64 KB bf16 H tile

    // ---- B-fragments (hh, o columns) -> registers, once ----
    short8 Bhh[16], Bo[16];
#pragma unroll
    for (int kk = 0; kk < 16; ++kk) {
        short8 bh, bo;
#pragma unroll
        for (int j = 0; j < 8; ++j) {
            int k = kk * 32 + kg * 8 + j;
            bh[j] = (short)f2bf(hh[(size_t)k * DIM + colw]);
            bo[j] = (short)f2bf(o [(size_t)k * DIM + colw]);
        }
        Bhh[kk] = bh; Bo[kk] = bo;
    }

    // ---- prefill hbuf slot 0 with broadcast h0 (all WGs write identical data) ----
    {
        unsigned long long* dst = hbuf + wv * 2048 + lane;
#pragma unroll 4
        for (int i = 0; i < 32; ++i) {
            // u64 i*64+lane within wave chunk: row = wv*16 + (i>>1), kelem = (i&1)*256 + lane*4
            float4 f = *reinterpret_cast<const float4*>(h0 + ((i & 1) << 8) + lane * 4);
            unsigned long long v = (unsigned long long)f2bf(f.x)
                | ((unsigned long long)f2bf(f.y) << 16)
                | ((unsigned long long)f2bf(f.z) << 32)
                | ((unsigned long long)f2bf(f.w) << 48);
            __hip_atomic_store(dst + i * 64, v, __ATOMIC_RELAXED, __HIP_MEMORY_SCOPE_AGENT);
        }
    }
    __builtin_amdgcn_fence(__ATOMIC_RELEASE, "agent");
    __syncthreads();

    // ---- prefetch XW for t=0 ----
    float xwr[16];
#pragma unroll
    for (int m = 0; m < 4; ++m)
#pragma unroll
        for (int r = 0; r < 4; ++r) {
            int row = m * 16 + kg * 4 + r;
            xwr[m * 4 + r] = out[((size_t)0 * BATCH + row) * DIM + colw];
        }

    for (int t = 0; t < TSTEPS; ++t) {
        // ---- stage H_t: coherence-point loads, lane-contiguous; swizzled LDS ----
        {
            const unsigned long long* src = hbuf + (size_t)(t & 3) * 8192 + wv * 2048 + lane;
#pragma unroll
            for (int ii = 0; ii < 32; ii += 8) {
                unsigned long long v[8];
#pragma unroll
                for (int j = 0; j < 8; ++j)
                    v[j] = __hip_atomic_load(src + (ii + j) * 64, __ATOMIC_RELAXED, __HIP_MEMORY_SCOPE_AGENT);
#pragma unroll
                for (int j = 0; j < 8; ++j) {
                    int i = ii + j;
                    int row = (wv << 4) + (i >> 1);
                    int byte = ((row << 10) + ((i & 1) << 9) + (lane << 3)) ^ ((row & 7) << 4);
                    hsU[byte >> 3] = v[j];
                }
            }
        }
        __syncthreads();

        // ---- MFMA: acc_h = H@hh, acc_y = H@o ----
        f32x4 acch[4], accy[4];
#pragma unroll
        for (int m = 0; m < 4; ++m) {
            acch[m] = f32x4{0.f, 0.f, 0.f, 0.f};
            accy[m] = f32x4{0.f, 0.f, 0.f, 0.f};
        }
#pragma unroll
        for (int kk = 0; kk < 16; ++kk) {
#pragma unroll
            for (int m = 0; m < 4; ++m) {
                int row = m * 16 + ln15;
                int byte = ((row << 10) + (kk << 6) + (kg << 4)) ^ ((row & 7) << 4);
                short8 a = *reinterpret_cast<const short8*>(
                    reinterpret_cast<const char*>(hsU) + byte);
                acch[m] = __builtin_amdgcn_mfma_f32_16x16x32_bf16(a, Bhh[kk], acch[m], 0, 0, 0);
                accy[m] = __builtin_amdgcn_mfma_f32_16x16x32_bf16(a, Bo[kk],  accy[m], 0, 0, 0);
            }
        }

        // ---- H_{t+1} = relu(XW_t + acc_h) -> hbuf slot (t+1)&3 ----
        {
            unsigned short* hdst = reinterpret_cast<unsigned short*>(hbuf + (size_t)((t + 1) & 3) * 8192);
#pragma unroll
            for (int m = 0; m < 4; ++m)
#pragma unroll
                for (int r = 0; r < 4; ++r) {
                    int row = m * 16 + kg * 4 + r;
                    float hn = xwr[m * 4 + r] + acch[m][r];
                    hn = hn > 0.f ? hn : 0.f;
                    __hip_atomic_store(hdst + (size_t)row * DIM + colw, f2bf(hn),
                                       __ATOMIC_RELAXED, __HIP_MEMORY_SCOPE_AGENT);
                }
        }
        __builtin_amdgcn_fence(__ATOMIC_RELEASE, "agent");
        __syncthreads();
        if (tid == 0)
            __hip_atomic_store(&flags[wg], (unsigned)(t + 1),
                               __ATOMIC_RELEASE, __HIP_MEMORY_SCOPE_AGENT);

        // ---- off-critical-path: y_{t-1} store + XW_{t+1} prefetch ----
        if (t >= 1) {
#pragma unroll
            for (int m = 0; m < 4; ++m)
#pragma unroll
                for (int r = 0; r < 4; ++r) {
                    int row = m * 16 + kg * 4 + r;
                    out[((size_t)(t - 1) * BATCH + row) * DIM + colw] = accy[m][r];
                }
        }
        if (t < TSTEPS - 1) {
#pragma unroll
            for (int m = 0; m < 4; ++m)
#pragma unroll
                for (int r = 0; r < 4; ++r) {
                    int row = m * 16 + kg * 4 + r;
                    xwr[m * 4 + r] = out[((size_t)(t + 1) * BATCH + row) * DIM + colw];
                }
        }

        // ---- barrier: all 8 flags >= t+1 ----
        if (wv == 0) {
            for (;;) {
                unsigned f = __hip_atomic_load(&flags[lane & (NWG - 1)],
                                               __ATOMIC_RELAXED, __HIP_MEMORY_SCOPE_AGENT);
                if (!__any(f < (unsigned)(t + 1))) break;
                __builtin_amdgcn_s_sleep(1);
            }
        }
        __syncthreads();
    }

    // ---- epilogue: y_{T-1} = H_T @ o ----
    {
        const unsigned long long* src = hbuf + (size_t)(TSTEPS & 3) * 8192 + wv * 2048 + lane;
#pragma unroll
        for (int ii = 0; ii < 32; ii += 8) {
            unsigned long long v[8];
#pragma unroll
            for (int j = 0; j < 8; ++j)
                v[j] = __hip_atomic_load(src + (ii + j) * 64, __ATOMIC_RELAXED, __HIP_MEMORY_SCOPE_AGENT);
#pragma unroll
            for (int j = 0; j < 8; ++j) {
                int i = ii + j;
                int row = (wv << 4) + (i >> 1);
                int byte = ((row << 10) + ((i & 1) << 9) + (lane << 3)) ^ ((row & 7) << 4);
                hsU[byte >> 3] = v[j];
            }
        }
        __syncthreads();
        f32x4 accy[4];
#pragma unroll
        for (int m = 0; m < 4; ++m) accy[m] = f32x4{0.f, 0.f, 0.f, 0.f};
#pragma unroll
        for (int kk = 0; kk < 16; ++kk) {
#pragma unroll
            for (int m = 0; m < 4; ++m) {
                int row = m * 16 + ln15;
                int byte = ((row << 10) + (kk << 6) + (kg << 4)) ^ ((row & 7) << 4);
                short8 a = *reinterpret_cast<const short8*>(
                    reinterpret_cast<const char*>(hsU) + byte);
                accy[m] = __builtin_amdgcn_mfma_f32_16x16x32_bf16(a, Bo[kk], accy[m], 0, 0, 0);
            }
        }
#pragma unroll
        for (int m = 0; m < 4; ++m)
#pragma unroll
            for (int r = 0; r < 4; ++r) {
                int row = m * 16 + kg * 4 + r;
                out[((size_t)(TSTEPS - 1) * BATCH + row) * DIM + colw] = accy[m][r];
            }
    }
}

extern "C" void kernel_launch(void* const* d_in, const int* in_sizes, int n_in,
                              void* d_out, int out_size, void* d_ws, size_t ws_size,
                              hipStream_t stream) {
    const float* x  = (const float*)d_in[0];
    const float* xh = (const float*)d_in[1];
    const float* hh = (const float*)d_in[2];
    const float* hb = (const float*)d_in[3];
    const float* o  = (const float*)d_in[4];
    const float* h0 = (const float*)d_in[5];
    float* out = (float*)d_out;

    unsigned int* flags = (unsigned int*)d_ws;
    unsigned long long* hbuf = (unsigned long long*)((char*)d_ws + 1024);  // 4 slots * 64KB

    (void)hipMemsetAsync(d_ws, 0, 256, stream);
    gemm_xw<<<dim3(512, 8), 256, 0, stream>>>(x, xh, hb, out);
    rnn_scan<<<NWG, 256, 0, stream>>>(hh, o, h0, out, hbuf, flags);
}

// Round 4
// 2492.496 us; speedup vs baseline: 7.8165x; 1.2274x over previous
//
#include <hip/hip_runtime.h>
#include <hip/hip_bf16.h>

#define TSTEPS 512
#define BATCH  64
#define DIM    512
#define NWG    8

using short8 = __attribute__((ext_vector_type(8))) short;
using f32x4  = __attribute__((ext_vector_type(4))) float;

__device__ __forceinline__ unsigned short f2bf(float f) {
    unsigned u = __builtin_bit_cast(unsigned, f);
    unsigned r = (u + 0x7FFFu + ((u >> 16) & 1u)) >> 16;   // RNE
    return (unsigned short)r;
}

// ---------- o (fp32 [k][col]) -> oT (bf16 [col][k]) ----------
__global__ void conv_oT(const float* __restrict__ src, unsigned short* __restrict__ dst) {
    __shared__ float tile[32][33];
    const int bx = blockIdx.x * 32, by = blockIdx.y * 32;
    const int tx = threadIdx.x & 31, ty = threadIdx.x >> 5;
#pragma unroll
    for (int k = 0; k < 32; k += 8)
        tile[ty + k][tx] = src[(size_t)(by + ty + k) * DIM + bx + tx];
    __syncthreads();
#pragma unroll
    for (int k = 0; k < 32; k += 8)
        dst[(size_t)(bx + ty + k) * DIM + by + tx] = f2bf(tile[tx][ty + k]);
}

// ---------- XW = x @ xh + hb -> d_out, remapped layout [t][kg][m][col][r] fp32 ----------
// Free register-transpose epilogue: float4 over i (rows 4ty..4ty+3 => r=i, kg=ty&3, m=ty>>2).
__global__ __launch_bounds__(256) void gemm_xw(
    const float* __restrict__ X, const float* __restrict__ W,
    const float* __restrict__ bias, float* __restrict__ Out)
{
    __shared__ float As[16][68];
    __shared__ float Bs[16][68];
    const int tid = threadIdx.x;
    const int m0 = blockIdx.x * 64, n0 = blockIdx.y * 64;
    const int tx = tid & 15, ty = tid >> 4;
    float acc[4][4] = {};
    for (int k0 = 0; k0 < DIM; k0 += 16) {
        {
            int r = tid >> 2, c = (tid & 3) * 4;
            float4 v = *reinterpret_cast<const float4*>(X + (size_t)(m0 + r) * DIM + k0 + c);
            As[c + 0][r] = v.x; As[c + 1][r] = v.y; As[c + 2][r] = v.z; As[c + 3][r] = v.w;
        }
        {
            int r = tid >> 4, c = (tid & 15) * 4;
            float4 v = *reinterpret_cast<const float4*>(W + (size_t)(k0 + r) * DIM + n0 + c);
            Bs[r][c + 0] = v.x; Bs[r][c + 1] = v.y; Bs[r][c + 2] = v.z; Bs[r][c + 3] = v.w;
        }
        __syncthreads();
#pragma unroll
        for (int k = 0; k < 16; ++k) {
            float4 a = *reinterpret_cast<const float4*>(&As[k][ty * 4]);
            float4 b = *reinterpret_cast<const float4*>(&Bs[k][tx * 4]);
            float av[4] = {a.x, a.y, a.z, a.w};
            float bv[4] = {b.x, b.y, b.z, b.w};
#pragma unroll
            for (int i = 0; i < 4; ++i)
#pragma unroll
                for (int j = 0; j < 4; ++j)
                    acc[i][j] = fmaf(av[i], bv[j], acc[i][j]);
        }
        __syncthreads();
    }
    float4 bv = *reinterpret_cast<const float4*>(bias + n0 + tx * 4);
    const float badd[4] = {bv.x, bv.y, bv.z, bv.w};
    // remapped store: t = blockIdx.x, kg = ty&3, m = ty>>2
    float4* Out4 = reinterpret_cast<float4*>(Out);
    const size_t base = (((size_t)blockIdx.x * 4 + (ty & 3)) * 4 + (ty >> 2)) * DIM + n0 + tx * 4;
#pragma unroll
    for (int j = 0; j < 4; ++j) {
        float4 v;
        v.x = acc[0][j] + badd[j]; v.y = acc[1][j] + badd[j];
        v.z = acc[2][j] + badd[j]; v.w = acc[3][j] + badd[j];
        Out4[base + j] = v;
    }
}

// ---------- persistent MFMA scan: hh-recurrence ONLY; writes full H history ----------
__global__ __launch_bounds__(256, 1) void rnn_scan(
    const float* __restrict__ hh, const float* __restrict__ xwb,
    const float* __restrict__ h0, unsigned long long* __restrict__ histU,
    unsigned int* __restrict__ flags)
{
    const int tid  = threadIdx.x;
    const int wg   = blockIdx.x;
    const int lane = tid & 63;
    const int wv   = __builtin_amdgcn_readfirstlane(tid >> 6);
    const int ln15 = lane & 15, kg = lane >> 4;
    const int colw = wg * 64 + wv * 16 + ln15;

    __shared__ unsigned long long hsU[BATCH * DIM / 4];  // 64 KB bf16 H tile

    // hh columns -> B-fragments, once
    short8 Bhh[16];
#pragma unroll
    for (int kk = 0; kk < 16; ++kk) {
        short8 bh;
#pragma unroll
        for (int j = 0; j < 8; ++j) {
            int k = kk * 32 + kg * 8 + j;
            bh[j] = (short)f2bf(hh[(size_t)k * DIM + colw]);
        }
        Bhh[kk] = bh;
    }

    // prefill hist slot 0 with broadcast h0 (all WGs write identical bytes)
    {
        unsigned long long* dst = histU + wv * 2048 + lane;
#pragma unroll 4
        for (int i = 0; i < 32; ++i) {
            float4 f = *reinterpret_cast<const float4*>(h0 + ((i & 1) << 8) + lane * 4);
            unsigned long long v = (unsigned long long)f2bf(f.x)
                | ((unsigned long long)f2bf(f.y) << 16)
                | ((unsigned long long)f2bf(f.z) << 32)
                | ((unsigned long long)f2bf(f.w) << 48);
            __hip_atomic_store(dst + i * 64, v, __ATOMIC_RELAXED, __HIP_MEMORY_SCOPE_AGENT);
        }
    }
    __builtin_amdgcn_fence(__ATOMIC_RELEASE, "agent");
    __syncthreads();

    const float4* xw4 = reinterpret_cast<const float4*>(xwb);
    f32x4 xwr[4];
#pragma unroll
    for (int m = 0; m < 4; ++m) {
        float4 v = xw4[(((size_t)0 * 4 + kg) * 4 + m) * DIM + colw];
        xwr[m] = f32x4{v.x, v.y, v.z, v.w};
    }

    for (int t = 0; t < TSTEPS; ++t) {
        // stage H_t (slot t) -> swizzled LDS
        {
            const unsigned long long* src = histU + (size_t)t * 8192 + wv * 2048 + lane;
#pragma unroll
            for (int ii = 0; ii < 32; ii += 8) {
                unsigned long long v[8];
#pragma unroll
                for (int j = 0; j < 8; ++j)
                    v[j] = __hip_atomic_load(src + (ii + j) * 64, __ATOMIC_RELAXED, __HIP_MEMORY_SCOPE_AGENT);
#pragma unroll
                for (int j = 0; j < 8; ++j) {
                    int i = ii + j;
                    int row = (wv << 4) + (i >> 1);
                    int byte = ((row << 10) + ((i & 1) << 9) + (lane << 3)) ^ ((row & 7) << 4);
                    hsU[byte >> 3] = v[j];
                }
            }
        }
        __syncthreads();

        f32x4 acch[4];
#pragma unroll
        for (int m = 0; m < 4; ++m) acch[m] = f32x4{0.f, 0.f, 0.f, 0.f};
#pragma unroll
        for (int kk = 0; kk < 16; ++kk) {
#pragma unroll
            for (int m = 0; m < 4; ++m) {
                int row = m * 16 + ln15;
                int byte = ((row << 10) + (kk << 6) + (kg << 4)) ^ ((row & 7) << 4);
                short8 a = *reinterpret_cast<const short8*>(
                    reinterpret_cast<const char*>(hsU) + byte);
                acch[m] = __builtin_amdgcn_mfma_f32_16x16x32_bf16(a, Bhh[kk], acch[m], 0, 0, 0);
            }
        }

        // H_{t+1} = relu(XW_t + acc) -> hist slot t+1
        {
            unsigned short* hdst = reinterpret_cast<unsigned short*>(histU + (size_t)(t + 1) * 8192);
#pragma unroll
            for (int m = 0; m < 4; ++m)
#pragma unroll
                for (int r = 0; r < 4; ++r) {
                    int row = m * 16 + kg * 4 + r;
                    float hn = xwr[m][r] + acch[m][r];
                    hn = hn > 0.f ? hn : 0.f;
                    __hip_atomic_store(hdst + (size_t)row * DIM + colw, f2bf(hn),
                                       __ATOMIC_RELAXED, __HIP_MEMORY_SCOPE_AGENT);
                }
        }
        __builtin_amdgcn_fence(__ATOMIC_RELEASE, "agent");
        __syncthreads();
        if (tid == 0)
            __hip_atomic_store(&flags[wg], (unsigned)(t + 1),
                               __ATOMIC_RELEASE, __HIP_MEMORY_SCOPE_AGENT);

        if (t < TSTEPS - 1) {
            // coalesced XW prefetch for t+1 (overlaps flag propagation)
#pragma unroll
            for (int m = 0; m < 4; ++m) {
                float4 v = xw4[(((size_t)(t + 1) * 4 + kg) * 4 + m) * DIM + colw];
                xwr[m] = f32x4{v.x, v.y, v.z, v.w};
            }
            // barrier: all 8 flags >= t+1
            if (wv == 0) {
                for (;;) {
                    unsigned f = __hip_atomic_load(&flags[lane & (NWG - 1)],
                                                   __ATOMIC_RELAXED, __HIP_MEMORY_SCOPE_AGENT);
                    if (!__any(f < (unsigned)(t + 1))) break;
                    __builtin_amdgcn_s_sleep(1);
                }
            }
            __syncthreads();
        }
    }
}

// ---------- Y = Hist(slots 1..512) @ o : MFMA GEMM, 128x128x32 tiles ----------
__global__ __launch_bounds__(256) void gemm_y(
    const unsigned short* __restrict__ A,   // hist + 32768: [32768][512] bf16
    const unsigned short* __restrict__ Bt,  // oT bf16 [col][k]
    float* __restrict__ Out)                // [32768][512] fp32
{
    __shared__ unsigned short As[128 * 40];  // LD=40 (pad) -> 2-way max on b128 reads
    __shared__ unsigned short Bs[128 * 40];
    const int tid = threadIdx.x;
    const int m0 = blockIdx.x * 128, n0 = blockIdx.y * 128;
    const int lane = tid & 63, wv = tid >> 6;
    const int ln15 = lane & 15, kg = lane >> 4;
    const int wr = (wv >> 1) * 64, wc = (wv & 1) * 64;

    f32x4 acc[4][4];
#pragma unroll
    for (int m = 0; m < 4; ++m)
#pragma unroll
        for (int n = 0; n < 4; ++n) acc[m][n] = f32x4{0.f, 0.f, 0.f, 0.f};

    const int sr = tid & 127;
    for (int k0 = 0; k0 < DIM; k0 += 32) {
        const unsigned short* g = (tid < 128)
            ? A  + (size_t)(m0 + sr) * DIM + k0
            : Bt + (size_t)(n0 + sr) * DIM + k0;
        unsigned short* s = (tid < 128) ? &As[sr * 40] : &Bs[sr * 40];
        ulonglong2 v0 = reinterpret_cast<const ulonglong2*>(g)[0];
        ulonglong2 v1 = reinterpret_cast<const ulonglong2*>(g)[1];
        ulonglong2 v2 = reinterpret_cast<const ulonglong2*>(g)[2];
        ulonglong2 v3 = reinterpret_cast<const ulonglong2*>(g)[3];
        __syncthreads();   // protect LDS reuse
        reinterpret_cast<ulonglong2*>(s)[0] = v0;
        reinterpret_cast<ulonglong2*>(s)[1] = v1;
        reinterpret_cast<ulonglong2*>(s)[2] = v2;
        reinterpret_cast<ulonglong2*>(s)[3] = v3;
        __syncthreads();
        short8 af[4], bf[4];
#pragma unroll
        for (int m = 0; m < 4; ++m)
            af[m] = *reinterpret_cast<const short8*>(&As[(wr + m * 16 + ln15) * 40 + kg * 8]);
#pragma unroll
        for (int n = 0; n < 4; ++n)
            bf[n] = *reinterpret_cast<const short8*>(&Bs[(wc + n * 16 + ln15) * 40 + kg * 8]);
#pragma unroll
        for (int m = 0; m < 4; ++m)
#pragma unroll
            for (int n = 0; n < 4; ++n)
                acc[m][n] = __builtin_amdgcn_mfma_f32_16x16x32_bf16(af[m], bf[n], acc[m][n], 0, 0, 0);
    }
#pragma unroll
    for (int m = 0; m < 4; ++m)
#pragma unroll
        for (int n = 0; n < 4; ++n)
#pragma unroll
            for (int r = 0; r < 4; ++r) {
                int row = m0 + wr + m * 16 + kg * 4 + r;
                int col = n0 + wc + n * 16 + ln15;
                Out[(size_t)row * DIM + col] = acc[m][n][r];
            }
}

extern "C" void kernel_launch(void* const* d_in, const int* in_sizes, int n_in,
                              void* d_out, int out_size, void* d_ws, size_t ws_size,
                              hipStream_t stream) {
    const float* x  = (const float*)d_in[0];
    const float* xh = (const float*)d_in[1];
    const float* hh = (const float*)d_in[2];
    const float* hb = (const float*)d_in[3];
    const float* o  = (const float*)d_in[4];
    const float* h0 = (const float*)d_in[5];
    float* out = (float*)d_out;

    unsigned int* flags = (unsigned int*)d_ws;
    unsigned long long* histU = (unsigned long long*)((char*)d_ws + 4096);   // 513 * 64KB
    unsigned short* oT = (unsigned short*)((char*)d_ws + 4096 + (size_t)513 * 65536);

    (void)hipMemsetAsync(d_ws, 0, 256, stream);
    conv_oT<<<dim3(16, 16), 256, 0, stream>>>(o, oT);
    gemm_xw<<<dim3(512, 8), 256, 0, stream>>>(x, xh, hb, out);   // out <- XWB (remapped)
    rnn_scan<<<NWG, 256, 0, stream>>>(hh, out, h0, histU, flags);
    gemm_y<<<dim3(256, 4), 256, 0, stream>>>(
        (const unsigned short*)histU + 32768, oT, out);          // out <- Y
}

// Round 6
// 2153.925 us; speedup vs baseline: 9.0451x; 1.1572x over previous
//
#include <hip/hip_runtime.h>
#include <hip/hip_bf16.h>

#define TSTEPS 512
#define BATCH  64
#define DIM    512
#define NWG    8

using short8 = __attribute__((ext_vector_type(8))) short;
using f32x4  = __attribute__((ext_vector_type(4))) float;

__device__ __forceinline__ unsigned short f2bf(float f) {
    unsigned u = __builtin_bit_cast(unsigned, f);
    unsigned r = (u + 0x7FFFu + ((u >> 16) & 1u)) >> 16;   // RNE
    return (unsigned short)r;
}

// ---------- fp32 [a][b] -> bf16 [b][a]  (for xh and o) ----------
__global__ void conv_T(const float* __restrict__ src, unsigned short* __restrict__ dst) {
    __shared__ float tile[32][33];
    const int bx = blockIdx.x * 32, by = blockIdx.y * 32;
    const int tx = threadIdx.x & 31, ty = threadIdx.x >> 5;
#pragma unroll
    for (int k = 0; k < 32; k += 8)
        tile[ty + k][tx] = src[(size_t)(by + ty + k) * DIM + bx + tx];
    __syncthreads();
#pragma unroll
    for (int k = 0; k < 32; k += 8)
        dst[(size_t)(bx + ty + k) * DIM + by + tx] = f2bf(tile[tx][ty + k]);
}

// ---------- XW = x @ xh + hb (bf16 MFMA) -> d_out, remapped [t][kg][m][col] float4(r) ----------
__global__ __launch_bounds__(256) void gemm_xwm(
    const float* __restrict__ X,            // [32768][512] fp32
    const unsigned short* __restrict__ Bt,  // xhT bf16 [col][k]
    const float* __restrict__ bias, float* __restrict__ Out)
{
    __shared__ unsigned short As[128 * 40];
    __shared__ unsigned short Bs[128 * 40];
    const int tid = threadIdx.x;
    const int m0 = blockIdx.x * 128, n0 = blockIdx.y * 128;
    const int lane = tid & 63, wv = tid >> 6;
    const int ln15 = lane & 15, kg = lane >> 4;
    const int wr = (wv >> 1) * 64, wc = (wv & 1) * 64;

    f32x4 acc[4][4];
#pragma unroll
    for (int m = 0; m < 4; ++m)
#pragma unroll
        for (int n = 0; n < 4; ++n) acc[m][n] = f32x4{0.f, 0.f, 0.f, 0.f};

    const int arow = tid >> 1, ahalf = tid & 1;      // 2 threads/row, 16 elements each
    for (int k0 = 0; k0 < DIM; k0 += 32) {
        const float4* ga = reinterpret_cast<const float4*>(
            X + (size_t)(m0 + arow) * DIM + k0 + ahalf * 16);
        float4 a0 = ga[0], a1 = ga[1], a2 = ga[2], a3 = ga[3];
        const ulonglong2* gb = reinterpret_cast<const ulonglong2*>(
            Bt + (size_t)(n0 + arow) * DIM + k0 + ahalf * 16);
        ulonglong2 bv0 = gb[0], bv1 = gb[1];         // FIX: full 16 bf16 (was 8)
        __syncthreads();   // protect LDS reuse from previous iteration reads
        {
            unsigned long long p[4];
            const float4 av[4] = {a0, a1, a2, a3};
#pragma unroll
            for (int q = 0; q < 4; ++q)
                p[q] = (unsigned long long)f2bf(av[q].x)
                     | ((unsigned long long)f2bf(av[q].y) << 16)
                     | ((unsigned long long)f2bf(av[q].z) << 32)
                     | ((unsigned long long)f2bf(av[q].w) << 48);
            unsigned long long* s = reinterpret_cast<unsigned long long*>(&As[arow * 40 + ahalf * 16]);
            s[0] = p[0]; s[1] = p[1]; s[2] = p[2]; s[3] = p[3];
            *reinterpret_cast<ulonglong2*>(&Bs[arow * 40 + ahalf * 16]) = bv0;
            *reinterpret_cast<ulonglong2*>(&Bs[arow * 40 + ahalf * 16 + 8]) = bv1;
        }
        __syncthreads();
        short8 af[4], bf[4];
#pragma unroll
        for (int m = 0; m < 4; ++m)
            af[m] = *reinterpret_cast<const short8*>(&As[(wr + m * 16 + ln15) * 40 + kg * 8]);
#pragma unroll
        for (int n = 0; n < 4; ++n)
            bf[n] = *reinterpret_cast<const short8*>(&Bs[(wc + n * 16 + ln15) * 40 + kg * 8]);
#pragma unroll
        for (int m = 0; m < 4; ++m)
#pragma unroll
            for (int n = 0; n < 4; ++n)
                acc[m][n] = __builtin_amdgcn_mfma_f32_16x16x32_bf16(af[m], bf[n], acc[m][n], 0, 0, 0);
    }
    // remapped epilogue: within-t row = m*16 + kg*4 + r; t = (m0+wr)>>6
    float4* Out4 = reinterpret_cast<float4*>(Out);
#pragma unroll
    for (int n = 0; n < 4; ++n) {
        int col = n0 + wc + n * 16 + ln15;
        float bb = bias[col];
#pragma unroll
        for (int m = 0; m < 4; ++m) {
            int t = (m0 + wr) >> 6;
            float4 v;
            v.x = acc[m][n][0] + bb; v.y = acc[m][n][1] + bb;
            v.z = acc[m][n][2] + bb; v.w = acc[m][n][3] + bb;
            Out4[(((size_t)t * 4 + kg) * 4 + m) * DIM + col] = v;
        }
    }
}

// ---------- persistent MFMA scan: hh-recurrence ONLY; writes full H history ----------
__global__ __launch_bounds__(256, 1) void rnn_scan(
    const float* __restrict__ hh, const float* __restrict__ xwb,
    const float* __restrict__ h0, unsigned long long* __restrict__ histU,
    unsigned int* __restrict__ flags)
{
    const int tid  = threadIdx.x;
    const int wg   = blockIdx.x;
    const int lane = tid & 63;
    const int wv   = __builtin_amdgcn_readfirstlane(tid >> 6);
    const int ln15 = lane & 15, kg = lane >> 4;
    const int colw = wg * 64 + wv * 16 + ln15;

    __shared__ unsigned long long hsU[BATCH * DIM / 4];  // 64 KB bf16 H tile

    short8 Bhh[16];
#pragma unroll
    for (int kk = 0; kk < 16; ++kk) {
        short8 bh;
#pragma unroll
        for (int j = 0; j < 8; ++j) {
            int k = kk * 32 + kg * 8 + j;
            bh[j] = (short)f2bf(hh[(size_t)k * DIM + colw]);
        }
        Bhh[kk] = bh;
    }

    // prefill hist slot 0 with broadcast h0 (all WGs write identical bytes)
    {
        unsigned long long* dst = histU + wv * 2048 + lane;
#pragma unroll 4
        for (int i = 0; i < 32; ++i) {
            float4 f = *reinterpret_cast<const float4*>(h0 + ((i & 1) << 8) + lane * 4);
            unsigned long long v = (unsigned long long)f2bf(f.x)
                | ((unsigned long long)f2bf(f.y) << 16)
                | ((unsigned long long)f2bf(f.z) << 32)
                | ((unsigned long long)f2bf(f.w) << 48);
            __hip_atomic_store(dst + i * 64, v, __ATOMIC_RELAXED, __HIP_MEMORY_SCOPE_AGENT);
        }
    }
    asm volatile("s_waitcnt vmcnt(0)" ::: "memory");
    __syncthreads();

    const float4* xw4 = reinterpret_cast<const float4*>(xwb);
    f32x4 xwr[4];
#pragma unroll
    for (int m = 0; m < 4; ++m) {
        float4 v = xw4[(((size_t)0 * 4 + kg) * 4 + m) * DIM + colw];
        xwr[m] = f32x4{v.x, v.y, v.z, v.w};
    }

    for (int t = 0; t < TSTEPS; ++t) {
        // stage H_t (slot t) -> swizzled LDS
        {
            const unsigned long long* src = histU + (size_t)t * 8192 + wv * 2048 + lane;
#pragma unroll
            for (int ii = 0; ii < 32; ii += 8) {
                unsigned long long v[8];
#pragma unroll
                for (int j = 0; j < 8; ++j)
                    v[j] = __hip_atomic_load(src + (ii + j) * 64, __ATOMIC_RELAXED, __HIP_MEMORY_SCOPE_AGENT);
#pragma unroll
                for (int j = 0; j < 8; ++j) {
                    int i = ii + j;
                    int row = (wv << 4) + (i >> 1);
                    int byte = ((row << 10) + ((i & 1) << 9) + (lane << 3)) ^ ((row & 7) << 4);
                    hsU[byte >> 3] = v[j];
                }
            }
        }
        __syncthreads();

        f32x4 acch[4];
#pragma unroll
        for (int m = 0; m < 4; ++m) acch[m] = f32x4{0.f, 0.f, 0.f, 0.f};
#pragma unroll
        for (int kk = 0; kk < 16; ++kk) {
#pragma unroll
            for (int m = 0; m < 4; ++m) {
                int row = m * 16 + ln15;
                int byte = ((row << 10) + (kk << 6) + (kg << 4)) ^ ((row & 7) << 4);
                short8 a = *reinterpret_cast<const short8*>(
                    reinterpret_cast<const char*>(hsU) + byte);
                acch[m] = __builtin_amdgcn_mfma_f32_16x16x32_bf16(a, Bhh[kk], acch[m], 0, 0, 0);
            }
        }

        // H_{t+1} = relu(XW_t + acc) -> hist slot t+1 (agent-scope atomic stores are
        // visible at the coherence point once ack'd; ordering = vmcnt(0) + barrier + flag)
        {
            unsigned short* hdst = reinterpret_cast<unsigned short*>(histU + (size_t)(t + 1) * 8192);
#pragma unroll
            for (int m = 0; m < 4; ++m)
#pragma unroll
                for (int r = 0; r < 4; ++r) {
                    int row = m * 16 + kg * 4 + r;
                    float hn = xwr[m][r] + acch[m][r];
                    hn = hn > 0.f ? hn : 0.f;
                    __hip_atomic_store(hdst + (size_t)row * DIM + colw, f2bf(hn),
                                       __ATOMIC_RELAXED, __HIP_MEMORY_SCOPE_AGENT);
                }
        }
        asm volatile("s_waitcnt vmcnt(0)" ::: "memory");   // stores ack'd at coherence point
        __syncthreads();                                    // all threads' stores done
        if (tid == 0)
            __hip_atomic_store(&flags[wg], (unsigned)(t + 1),
                               __ATOMIC_RELAXED, __HIP_MEMORY_SCOPE_AGENT);

        if (t < TSTEPS - 1) {
            // coalesced XW prefetch for t+1 (overlaps flag propagation / poll)
#pragma unroll
            for (int m = 0; m < 4; ++m) {
                float4 v = xw4[(((size_t)(t + 1) * 4 + kg) * 4 + m) * DIM + colw];
                xwr[m] = f32x4{v.x, v.y, v.z, v.w};
            }
            if (wv == 0) {
                for (;;) {
                    unsigned f = __hip_atomic_load(&flags[lane & (NWG - 1)],
                                                   __ATOMIC_RELAXED, __HIP_MEMORY_SCOPE_AGENT);
                    if (!__any(f < (unsigned)(t + 1))) break;
                    __builtin_amdgcn_s_sleep(1);
                }
            }
            __syncthreads();
        }
    }
}

// ---------- Y = Hist(slots 1..512) @ o : MFMA GEMM, 128x128x32 tiles ----------
__global__ __launch_bounds__(256) void gemm_y(
    const unsigned short* __restrict__ A,   // hist + 32768: [32768][512] bf16
    const unsigned short* __restrict__ Bt,  // oT bf16 [col][k]
    float* __restrict__ Out)                // [32768][512] fp32
{
    __shared__ unsigned short As[128 * 40];
    __shared__ unsigned short Bs[128 * 40];
    const int tid = threadIdx.x;
    const int m0 = blockIdx.x * 128, n0 = blockIdx.y * 128;
    const int lane = tid & 63, wv = tid >> 6;
    const int ln15 = lane & 15, kg = lane >> 4;
    const int wr = (wv >> 1) * 64, wc = (wv & 1) * 64;

    f32x4 acc[4][4];
#pragma unroll
    for (int m = 0; m < 4; ++m)
#pragma unroll
        for (int n = 0; n < 4; ++n) acc[m][n] = f32x4{0.f, 0.f, 0.f, 0.f};

    const int sr = tid & 127;
    for (int k0 = 0; k0 < DIM; k0 += 32) {
        const unsigned short* g = (tid < 128)
            ? A  + (size_t)(m0 + sr) * DIM + k0
            : Bt + (size_t)(n0 + sr) * DIM + k0;
        unsigned short* s = (tid < 128) ? &As[sr * 40] : &Bs[sr * 40];
        ulonglong2 v0 = reinterpret_cast<const ulonglong2*>(g)[0];
        ulonglong2 v1 = reinterpret_cast<const ulonglong2*>(g)[1];
        ulonglong2 v2 = reinterpret_cast<const ulonglong2*>(g)[2];
        ulonglong2 v3 = reinterpret_cast<const ulonglong2*>(g)[3];
        __syncthreads();
        reinterpret_cast<ulonglong2*>(s)[0] = v0;
        reinterpret_cast<ulonglong2*>(s)[1] = v1;
        reinterpret_cast<ulonglong2*>(s)[2] = v2;
        reinterpret_cast<ulonglong2*>(s)[3] = v3;
        __syncthreads();
        short8 af[4], bf[4];
#pragma unroll
        for (int m = 0; m < 4; ++m)
            af[m] = *reinterpret_cast<const short8*>(&As[(wr + m * 16 + ln15) * 40 + kg * 8]);
#pragma unroll
        for (int n = 0; n < 4; ++n)
            bf[n] = *reinterpret_cast<const short8*>(&Bs[(wc + n * 16 + ln15) * 40 + kg * 8]);
#pragma unroll
        for (int m = 0; m < 4; ++m)
#pragma unroll
            for (int n = 0; n < 4; ++n)
                acc[m][n] = __builtin_amdgcn_mfma_f32_16x16x32_bf16(af[m], bf[n], acc[m][n], 0, 0, 0);
    }
#pragma unroll
    for (int m = 0; m < 4; ++m)
#pragma unroll
        for (int n = 0; n < 4; ++n)
#pragma unroll
            for (int r = 0; r < 4; ++r) {
                int row = m0 + wr + m * 16 + kg * 4 + r;
                int col = n0 + wc + n * 16 + ln15;
                Out[(size_t)row * DIM + col] = acc[m][n][r];
            }
}

extern "C" void kernel_launch(void* const* d_in, const int* in_sizes, int n_in,
                              void* d_out, int out_size, void* d_ws, size_t ws_size,
                              hipStream_t stream) {
    const float* x  = (const float*)d_in[0];
    const float* xh = (const float*)d_in[1];
    const float* hh = (const float*)d_in[2];
    const float* hb = (const float*)d_in[3];
    const float* o  = (const float*)d_in[4];
    const float* h0 = (const float*)d_in[5];
    float* out = (float*)d_out;

    unsigned int* flags = (unsigned int*)d_ws;
    unsigned long long* histU = (unsigned long long*)((char*)d_ws + 4096);     // 513*64KB
    unsigned short* oT  = (unsigned short*)((char*)d_ws + 4096 + (size_t)513 * 65536);
    unsigned short* xhT = oT + (size_t)DIM * DIM;

    (void)hipMemsetAsync(d_ws, 0, 256, stream);
    conv_T<<<dim3(16, 16), 256, 0, stream>>>(o, oT);
    conv_T<<<dim3(16, 16), 256, 0, stream>>>(xh, xhT);
    gemm_xwm<<<dim3(256, 4), 256, 0, stream>>>(x, xhT, hb, out);   // out <- XWB (remapped)
    rnn_scan<<<NWG, 256, 0, stream>>>(hh, out, h0, histU, flags);
    gemm_y<<<dim3(256, 4), 256, 0, stream>>>(
        (const unsigned short*)histU + 32768, oT, out);            // out <- Y
}